// Round 1
// baseline (476.142 us; speedup 1.0000x reference)
//
#include <hip/hip_runtime.h>

#define DIM 128
#define CLS 40

// ---------------- CSR build (mask = conf > 0.5, indexed by dst) ----------------

__global__ void zero_cnt_kernel(int* __restrict__ cnt, int n) {
  int i = blockIdx.x * 256 + threadIdx.x;
  if (i < n) cnt[i] = 0;
}

__global__ void hist_kernel(const int* __restrict__ ei, const float* __restrict__ conf,
                            int* __restrict__ cnt, int E) {
  int e = blockIdx.x * 256 + threadIdx.x;
  if (e < E && conf[e] > 0.5f) atomicAdd(&cnt[ei[E + e]], 1);
}

__global__ __launch_bounds__(1024) void scan_kernel(const int* __restrict__ cnt,
                                                    int* __restrict__ off,
                                                    int* __restrict__ pos, int n) {
  __shared__ int wsum[16];
  __shared__ int carry_s;
  int lane = threadIdx.x & 63;
  int wid = threadIdx.x >> 6;
  if (threadIdx.x == 0) carry_s = 0;
  __syncthreads();
  for (int base = 0; base < n; base += 1024) {
    int i = base + (int)threadIdx.x;
    int v = (i < n) ? cnt[i] : 0;
    int s = v;
#pragma unroll
    for (int o = 1; o < 64; o <<= 1) {
      int t = __shfl_up(s, o);
      if (lane >= o) s += t;
    }
    if (lane == 63) wsum[wid] = s;
    __syncthreads();
    if (wid == 0) {
      int w = (lane < 16) ? wsum[lane] : 0;
#pragma unroll
      for (int o = 1; o < 16; o <<= 1) {
        int t = __shfl_up(w, o);
        if (lane >= o) w += t;
      }
      if (lane < 16) wsum[lane] = w;
    }
    __syncthreads();
    int carry = carry_s;
    int wbase = (wid == 0) ? 0 : wsum[wid - 1];
    int excl = carry + wbase + s - v;
    if (i < n) { off[i] = excl; pos[i] = excl; }
    int tot = wsum[15];
    __syncthreads();
    if (threadIdx.x == 0) carry_s = carry + tot;
    __syncthreads();
  }
  if (threadIdx.x == 0) off[n] = carry_s;
}

__global__ void fill_kernel(const int* __restrict__ ei, const float* __restrict__ conf,
                            int* __restrict__ pos, int* __restrict__ esrc, int E) {
  int e = blockIdx.x * 256 + threadIdx.x;
  if (e < E && conf[e] > 0.5f) {
    int p = atomicAdd(&pos[ei[E + e]], 1);
    esrc[p] = ei[e];
  }
}

// ---------------- per-layer kernels ----------------

// enc[n,k] = relu(sum_d We[c,k,d]*h[n,d] + be[c,k]); 0 if label<0. One wave per node.
__global__ __launch_bounds__(256) void enc_kernel(const float* __restrict__ h,
                                                  const int* __restrict__ labels,
                                                  const float* __restrict__ We,
                                                  const float* __restrict__ be,
                                                  float* __restrict__ enc, int N) {
  int wid = threadIdx.x >> 6;
  int lane = threadIdx.x & 63;
  int n = blockIdx.x * 4 + wid;
  if (n >= N) return;
  int c = labels[n];
  int sc = c < 0 ? 0 : c;
  const float* wb = We + (size_t)sc * 4 * DIM;
  float h0 = h[(size_t)n * DIM + lane];
  float h1 = h[(size_t)n * DIM + 64 + lane];
  float p0 = wb[0 * DIM + lane] * h0 + wb[0 * DIM + 64 + lane] * h1;
  float p1 = wb[1 * DIM + lane] * h0 + wb[1 * DIM + 64 + lane] * h1;
  float p2 = wb[2 * DIM + lane] * h0 + wb[2 * DIM + 64 + lane] * h1;
  float p3 = wb[3 * DIM + lane] * h0 + wb[3 * DIM + 64 + lane] * h1;
#pragma unroll
  for (int o = 32; o > 0; o >>= 1) {
    p0 += __shfl_xor(p0, o);
    p1 += __shfl_xor(p1, o);
    p2 += __shfl_xor(p2, o);
    p3 += __shfl_xor(p3, o);
  }
  if (lane == 0) {
    const float* bb = be + sc * 4;
    float4 r;
    r.x = (c < 0) ? 0.f : fmaxf(p0 + bb[0], 0.f);
    r.y = (c < 0) ? 0.f : fmaxf(p1 + bb[1], 0.f);
    r.z = (c < 0) ? 0.f : fmaxf(p2 + bb[2], 0.f);
    r.w = (c < 0) ? 0.f : fmaxf(p3 + bb[3], 0.f);
    *(float4*)&enc[n * 4] = r;
  }
}

// agg[n,d] = (1/cnt) * sum_{edges} relu(Wd[c,d,:]·enc[src] + bd[c,d]); 128 threads per node.
__global__ __launch_bounds__(256) void agg_kernel(const float* __restrict__ enc,
                                                  const int* __restrict__ labels,
                                                  const int* __restrict__ off,
                                                  const int* __restrict__ esrc,
                                                  const float* __restrict__ Wd,
                                                  const float* __restrict__ bd,
                                                  float* __restrict__ agg, int N) {
  int half = threadIdx.x >> 7;
  int d = threadIdx.x & 127;
  int n = blockIdx.x * 2 + half;
  if (n >= N) return;
  int c = labels[n];
  int j0 = off[n], j1 = off[n + 1];
  int cnt = j1 - j0;
  float outv = 0.f;
  if (c >= 0 && cnt > 0) {
    const float4 w = *(const float4*)&Wd[((size_t)c * DIM + d) * 4];
    const float bb = bd[(size_t)c * DIM + d];
    float acc = 0.f;
    for (int j = j0; j < j1; ++j) {
      int s = esrc[j];
      float4 m = *(const float4*)&enc[s * 4];
      float v = fmaf(w.x, m.x, fmaf(w.y, m.y, fmaf(w.z, m.z, fmaf(w.w, m.w, bb))));
      acc += fmaxf(v, 0.f);
    }
    outv = acc / (float)cnt;
  }
  agg[(size_t)n * DIM + d] = outv;
}

// WT[k][j]: rows 0..127 = Wl^T, rows 128..255 = Wr^T. Also zeroes BN stats.
__global__ void wt_kernel(const float* __restrict__ Wl, const float* __restrict__ Wr,
                          float* __restrict__ WT, float* __restrict__ stats, int ncol) {
  int idx = blockIdx.x * 256 + threadIdx.x;
  if (idx < 256) stats[idx] = 0.f;
  if (idx < 256 * ncol) {
    int k = idx / ncol, j = idx - k * ncol;
    WT[idx] = (k < 128) ? Wl[j * 128 + k] : Wr[j * 128 + (k - 128)];
  }
}

// out[n,j] = bias[j] + sum_k agg[n,k]*Wl[j,k] + sum_k h[n,k]*Wr[j,k]
// 64-row tiles, K staged in 8 chunks of 32, 4x8 (or 4x4) register tile per thread.
template <int NCOL>
__global__ __launch_bounds__(256) void linear_kernel(const float* __restrict__ agg,
                                                     const float* __restrict__ h,
                                                     const float* __restrict__ WT,
                                                     const float* __restrict__ bias,
                                                     float* __restrict__ out, int N) {
  __shared__ float Ilds[32][65];       // transposed input tile [k][row]
  __shared__ float Wlds[32 * NCOL];    // [k][j]
  const int tid = threadIdx.x;
  const int tx = tid & 15;
  const int ty = tid >> 4;
  const int r0 = blockIdx.x * 64;
  constexpr int NJ = (NCOL == 128) ? 8 : 4;
  float acc[4][NJ];
#pragma unroll
  for (int i = 0; i < 4; ++i)
#pragma unroll
    for (int j = 0; j < NJ; ++j) acc[i][j] = 0.f;

  const int kp = (tid & 7) * 4;
  const int rr = tid >> 3;  // 0..31

  for (int kc = 0; kc < 8; ++kc) {
    const float* __restrict__ src = (kc < 4) ? agg : h;
    const int kb = (kc & 3) * 32;
    // stage input (transposed, padded)
#pragma unroll
    for (int pass = 0; pass < 2; ++pass) {
      int r = rr + pass * 32;
      int row = r0 + r;
      float4 v = make_float4(0.f, 0.f, 0.f, 0.f);
      if (row < N) v = *(const float4*)&src[(size_t)row * DIM + kb + kp];
      Ilds[kp + 0][r] = v.x;
      Ilds[kp + 1][r] = v.y;
      Ilds[kp + 2][r] = v.z;
      Ilds[kp + 3][r] = v.w;
    }
    // stage W chunk (coalesced from pre-transposed WT)
    {
      const float4* wsrc = (const float4*)&WT[kc * 32 * NCOL];
      float4* wdst = (float4*)Wlds;
      constexpr int NV = 32 * NCOL / 4;
#pragma unroll
      for (int i = 0; i < (NV + 255) / 256; ++i) {
        int idx = tid + i * 256;
        if ((NV % 256 == 0) || idx < NV) wdst[idx] = wsrc[idx];
      }
    }
    __syncthreads();
#pragma unroll
    for (int kk = 0; kk < 32; ++kk) {
      if constexpr (NCOL == 128) {
        float4 w0 = *(const float4*)&Wlds[kk * 128 + tx * 4];
        float4 w1 = *(const float4*)&Wlds[kk * 128 + 64 + tx * 4];
#pragma unroll
        for (int i = 0; i < 4; ++i) {
          float a = Ilds[kk][ty * 4 + i];
          acc[i][0] = fmaf(a, w0.x, acc[i][0]);
          acc[i][1] = fmaf(a, w0.y, acc[i][1]);
          acc[i][2] = fmaf(a, w0.z, acc[i][2]);
          acc[i][3] = fmaf(a, w0.w, acc[i][3]);
          acc[i][4] = fmaf(a, w1.x, acc[i][4]);
          acc[i][5] = fmaf(a, w1.y, acc[i][5]);
          acc[i][6] = fmaf(a, w1.z, acc[i][6]);
          acc[i][7] = fmaf(a, w1.w, acc[i][7]);
        }
      } else {
        if (tx < 10) {
          float4 w0 = *(const float4*)&Wlds[kk * NCOL + tx * 4];
#pragma unroll
          for (int i = 0; i < 4; ++i) {
            float a = Ilds[kk][ty * 4 + i];
            acc[i][0] = fmaf(a, w0.x, acc[i][0]);
            acc[i][1] = fmaf(a, w0.y, acc[i][1]);
            acc[i][2] = fmaf(a, w0.z, acc[i][2]);
            acc[i][3] = fmaf(a, w0.w, acc[i][3]);
          }
        }
      }
    }
    __syncthreads();
  }

  if constexpr (NCOL == 128) {
    float4 b0 = *(const float4*)&bias[tx * 4];
    float4 b1 = *(const float4*)&bias[64 + tx * 4];
#pragma unroll
    for (int i = 0; i < 4; ++i) {
      int row = r0 + ty * 4 + i;
      if (row < N) {
        float4 o0 = make_float4(acc[i][0] + b0.x, acc[i][1] + b0.y, acc[i][2] + b0.z,
                                acc[i][3] + b0.w);
        float4 o1 = make_float4(acc[i][4] + b1.x, acc[i][5] + b1.y, acc[i][6] + b1.z,
                                acc[i][7] + b1.w);
        *(float4*)&out[(size_t)row * 128 + tx * 4] = o0;
        *(float4*)&out[(size_t)row * 128 + 64 + tx * 4] = o1;
      }
    }
  } else {
    if (tx < 10) {
      float4 b0 = *(const float4*)&bias[tx * 4];
#pragma unroll
      for (int i = 0; i < 4; ++i) {
        int row = r0 + ty * 4 + i;
        if (row < N) {
          float4 o0 = make_float4(acc[i][0] + b0.x, acc[i][1] + b0.y, acc[i][2] + b0.z,
                                  acc[i][3] + b0.w);
          *(float4*)&out[(size_t)row * CLS + tx * 4] = o0;
        }
      }
    }
  }
}

// BN stats: stats[0..127]=col sums, stats[128..255]=col sumsq
__global__ __launch_bounds__(256) void bnstats_kernel(const float* __restrict__ h1,
                                                      float* __restrict__ stats, int N) {
  __shared__ float l1[256], l2[256];
  int col = threadIdx.x & 127;
  int rs = threadIdx.x >> 7;
  float s = 0.f, s2 = 0.f;
  for (int n = blockIdx.x * 2 + rs; n < N; n += gridDim.x * 2) {
    float v = h1[(size_t)n * DIM + col];
    s += v;
    s2 = fmaf(v, v, s2);
  }
  l1[threadIdx.x] = s;
  l2[threadIdx.x] = s2;
  __syncthreads();
  if (threadIdx.x < 128) {
    s = l1[threadIdx.x] + l1[threadIdx.x + 128];
    s2 = l2[threadIdx.x] + l2[threadIdx.x + 128];
    atomicAdd(&stats[col], s);
    atomicAdd(&stats[DIM + col], s2);
  }
}

// in-place: h = relu(gamma*(h1-mu)*rsqrt(var+eps)+beta)
__global__ __launch_bounds__(256) void bnnorm_kernel(float* __restrict__ h,
                                                     const float* __restrict__ stats,
                                                     const float* __restrict__ gamma,
                                                     const float* __restrict__ beta, int N) {
  int idx = blockIdx.x * 256 + threadIdx.x;  // over N*32 float4s
  if (idx >= N * 32) return;
  int c4 = (idx & 31) * 4;
  float inv = 1.f / (float)N;
  float4 sm = *(const float4*)&stats[c4];
  float4 sq = *(const float4*)&stats[DIM + c4];
  float4 g = *(const float4*)&gamma[c4];
  float4 b = *(const float4*)&beta[c4];
  float4 v = *(float4*)&h[(size_t)idx * 4];
  float mu, var, r;
  mu = sm.x * inv; var = sq.x * inv - mu * mu; r = rsqrtf(var + 1e-5f);
  v.x = fmaxf(fmaf(g.x * (v.x - mu), r, b.x), 0.f);
  mu = sm.y * inv; var = sq.y * inv - mu * mu; r = rsqrtf(var + 1e-5f);
  v.y = fmaxf(fmaf(g.y * (v.y - mu), r, b.y), 0.f);
  mu = sm.z * inv; var = sq.z * inv - mu * mu; r = rsqrtf(var + 1e-5f);
  v.z = fmaxf(fmaf(g.z * (v.z - mu), r, b.z), 0.f);
  mu = sm.w * inv; var = sq.w * inv - mu * mu; r = rsqrtf(var + 1e-5f);
  v.w = fmaxf(fmaf(g.w * (v.w - mu), r, b.w), 0.f);
  *(float4*)&h[(size_t)idx * 4] = v;
}

// ---------------- host ----------------

extern "C" void kernel_launch(void* const* d_in, const int* in_sizes, int n_in,
                              void* d_out, int out_size, void* d_ws, size_t ws_size,
                              hipStream_t stream) {
  const float* x      = (const float*)d_in[0];
  const int*   ei     = (const int*)d_in[1];
  const int*   labels = (const int*)d_in[2];
  const float* conf   = (const float*)d_in[3];
  const float* W_enc  = (const float*)d_in[4];
  const float* b_enc  = (const float*)d_in[5];
  const float* W_dec  = (const float*)d_in[6];
  const float* b_dec  = (const float*)d_in[7];
  const float* Wl01   = (const float*)d_in[8];
  const float* bl01   = (const float*)d_in[9];
  const float* Wr01   = (const float*)d_in[10];
  const float* Wl2    = (const float*)d_in[11];
  const float* bl2    = (const float*)d_in[12];
  const float* Wr2    = (const float*)d_in[13];
  const float* gamma  = (const float*)d_in[14];
  const float* beta   = (const float*)d_in[15];
  float* out = (float*)d_out;

  const int N = in_sizes[2];
  const int E = in_sizes[3];

  char* ws = (char*)d_ws;
  size_t o = 0;
  auto alloc = [&](size_t bytes) -> void* {
    void* p = ws + o;
    o += (bytes + 255) & ~(size_t)255;
    return p;
  };
  int* cnt    = (int*)alloc((size_t)N * 4);
  int* off    = (int*)alloc(((size_t)N + 1) * 4);
  int* pos    = (int*)alloc((size_t)N * 4);
  int* esrc   = (int*)alloc((size_t)E * 4);
  float* enc  = (float*)alloc((size_t)N * 4 * 4);
  float* agg  = (float*)alloc((size_t)N * DIM * 4);
  float* hbuf = (float*)alloc((size_t)N * DIM * 4);
  float* WT   = (float*)alloc(256 * DIM * 4);
  float* stats = (float*)alloc(256 * 4);
  (void)ws_size; (void)n_in; (void)out_size;

  zero_cnt_kernel<<<(N + 255) / 256, 256, 0, stream>>>(cnt, N);
  hist_kernel<<<(E + 255) / 256, 256, 0, stream>>>(ei, conf, cnt, E);
  scan_kernel<<<1, 1024, 0, stream>>>(cnt, off, pos, N);
  fill_kernel<<<(E + 255) / 256, 256, 0, stream>>>(ei, conf, pos, esrc, E);

  const float* hin = x;
  for (int l = 0; l < 3; ++l) {
    const float* We = W_enc + (size_t)l * CLS * 4 * DIM;
    const float* be = b_enc + (size_t)l * CLS * 4;
    const float* Wd = W_dec + (size_t)l * CLS * DIM * 4;
    const float* bd = b_dec + (size_t)l * CLS * DIM;
    enc_kernel<<<(N + 3) / 4, 256, 0, stream>>>(hin, labels, We, be, enc, N);
    agg_kernel<<<(N + 1) / 2, 256, 0, stream>>>(enc, labels, off, esrc, Wd, bd, agg, N);
    if (l < 2) {
      const float* Wl = Wl01 + (size_t)l * DIM * DIM;
      const float* Wr = Wr01 + (size_t)l * DIM * DIM;
      const float* bl = bl01 + (size_t)l * DIM;
      wt_kernel<<<DIM, 256, 0, stream>>>(Wl, Wr, WT, stats, DIM);
      linear_kernel<128><<<(N + 63) / 64, 256, 0, stream>>>(agg, hin, WT, bl, hbuf, N);
      bnstats_kernel<<<256, 256, 0, stream>>>(hbuf, stats, N);
      bnnorm_kernel<<<(N * 32 + 255) / 256, 256, 0, stream>>>(hbuf, stats, gamma + l * DIM,
                                                              beta + l * DIM, N);
      hin = hbuf;
    } else {
      wt_kernel<<<CLS, 256, 0, stream>>>(Wl2, Wr2, WT, stats, CLS);
      linear_kernel<40><<<(N + 63) / 64, 256, 0, stream>>>(agg, hin, WT, bl2, out, N);
    }
  }
}

// Round 2
// 374.658 us; speedup vs baseline: 1.2709x; 1.2709x over previous
//
#include <hip/hip_runtime.h>

#define DIM 128
#define CLS 40

typedef __attribute__((ext_vector_type(8))) short bf16x8;
typedef __attribute__((ext_vector_type(4))) float f32x4;

__device__ __forceinline__ ushort f2bf(float f) {
  uint u = __float_as_uint(f);
  u += 0x7FFFu + ((u >> 16) & 1u);
  return (ushort)(u >> 16);
}
__device__ __forceinline__ float bf2f(ushort h) {
  return __uint_as_float(((uint)h) << 16);
}

// ---------------- CSR build (mask = conf > 0.5, indexed by dst) ----------------

__global__ void zero_cnt_kernel(int* __restrict__ cnt, int n) {
  int i = blockIdx.x * 256 + threadIdx.x;
  if (i < n) cnt[i] = 0;
}

__global__ void hist_kernel(const int* __restrict__ ei, const float* __restrict__ conf,
                            int* __restrict__ cnt, int E) {
  int e = blockIdx.x * 256 + threadIdx.x;
  if (e < E && conf[e] > 0.5f) atomicAdd(&cnt[ei[E + e]], 1);
}

// 4-wide single-block scan: off = exclusive prefix of cnt, pos = copy of off.
__global__ __launch_bounds__(1024) void scan_kernel(const int* __restrict__ cnt,
                                                    int* __restrict__ off,
                                                    int* __restrict__ pos, int n) {
  __shared__ int wsum[16];
  __shared__ int carry_s;
  int lane = threadIdx.x & 63;
  int wid = threadIdx.x >> 6;
  if (threadIdx.x == 0) carry_s = 0;
  __syncthreads();
  int n4 = (n + 3) >> 2;
  for (int base = 0; base < n4; base += 1024) {
    int i4 = base + (int)threadIdx.x;
    int4 v = make_int4(0, 0, 0, 0);
    int i0 = i4 * 4;
    if (i0 + 3 < n) {
      v = *(const int4*)&cnt[i0];
    } else if (i0 < n) {
      v.x = cnt[i0];
      if (i0 + 1 < n) v.y = cnt[i0 + 1];
      if (i0 + 2 < n) v.z = cnt[i0 + 2];
    }
    int s4 = v.x + v.y + v.z + v.w;
    int s = s4;
#pragma unroll
    for (int o = 1; o < 64; o <<= 1) {
      int t = __shfl_up(s, o);
      if (lane >= o) s += t;
    }
    if (lane == 63) wsum[wid] = s;
    __syncthreads();
    if (wid == 0) {
      int w = (lane < 16) ? wsum[lane] : 0;
#pragma unroll
      for (int o = 1; o < 16; o <<= 1) {
        int t = __shfl_up(w, o);
        if (lane >= o) w += t;
      }
      if (lane < 16) wsum[lane] = w;
    }
    __syncthreads();
    int carry = carry_s;
    int wbase = (wid == 0) ? 0 : wsum[wid - 1];
    int excl = carry + wbase + s - s4;
    if (i0 < n) {
      int e0 = excl, e1 = e0 + v.x, e2 = e1 + v.y, e3 = e2 + v.z;
      off[i0] = e0; pos[i0] = e0;
      if (i0 + 1 < n) { off[i0 + 1] = e1; pos[i0 + 1] = e1; }
      if (i0 + 2 < n) { off[i0 + 2] = e2; pos[i0 + 2] = e2; }
      if (i0 + 3 < n) { off[i0 + 3] = e3; pos[i0 + 3] = e3; }
    }
    int tot = wsum[15];
    __syncthreads();
    if (threadIdx.x == 0) carry_s = carry + tot;
    __syncthreads();
  }
  if (threadIdx.x == 0) off[n] = carry_s;
}

__global__ void fill_kernel(const int* __restrict__ ei, const float* __restrict__ conf,
                            int* __restrict__ pos, int* __restrict__ esrc, int E) {
  int e = blockIdx.x * 256 + threadIdx.x;
  if (e < E && conf[e] > 0.5f) {
    int p = atomicAdd(&pos[ei[E + e]], 1);
    esrc[p] = ei[e];
  }
}

// ---------------- per-layer kernels ----------------

// Optionally applies BN(relu) of the PREVIOUS layer in-place on h (useBN),
// then enc[n,k] = relu(sum_d We[c,k,d]*h[n,d] + be[c,k]); 0 if label<0.
__global__ __launch_bounds__(256) void enc_kernel(const float* __restrict__ hin,
                                                  const int* __restrict__ labels,
                                                  const float* __restrict__ We,
                                                  const float* __restrict__ be,
                                                  float* __restrict__ enc,
                                                  float* __restrict__ hout,
                                                  const float* __restrict__ stats,
                                                  const float* __restrict__ gamma,
                                                  const float* __restrict__ beta,
                                                  int useBN, int N) {
  int wid = threadIdx.x >> 6;
  int lane = threadIdx.x & 63;
  int n = blockIdx.x * 4 + wid;
  if (n >= N) return;
  int c = labels[n];
  int sc = c < 0 ? 0 : c;
  float h0 = hin[(size_t)n * DIM + lane];
  float h1 = hin[(size_t)n * DIM + 64 + lane];
  if (useBN) {
    float inv = 1.f / (float)N;
    int c0 = lane, c1 = 64 + lane;
    float mu0 = stats[c0] * inv, mu1 = stats[c1] * inv;
    float va0 = stats[DIM + c0] * inv - mu0 * mu0;
    float va1 = stats[DIM + c1] * inv - mu1 * mu1;
    h0 = fmaxf(fmaf(gamma[c0] * (h0 - mu0), rsqrtf(va0 + 1e-5f), beta[c0]), 0.f);
    h1 = fmaxf(fmaf(gamma[c1] * (h1 - mu1), rsqrtf(va1 + 1e-5f), beta[c1]), 0.f);
    hout[(size_t)n * DIM + lane] = h0;
    hout[(size_t)n * DIM + 64 + lane] = h1;
  }
  const float* wb = We + (size_t)sc * 4 * DIM;
  float p0 = wb[0 * DIM + lane] * h0 + wb[0 * DIM + 64 + lane] * h1;
  float p1 = wb[1 * DIM + lane] * h0 + wb[1 * DIM + 64 + lane] * h1;
  float p2 = wb[2 * DIM + lane] * h0 + wb[2 * DIM + 64 + lane] * h1;
  float p3 = wb[3 * DIM + lane] * h0 + wb[3 * DIM + 64 + lane] * h1;
#pragma unroll
  for (int o = 32; o > 0; o >>= 1) {
    p0 += __shfl_xor(p0, o);
    p1 += __shfl_xor(p1, o);
    p2 += __shfl_xor(p2, o);
    p3 += __shfl_xor(p3, o);
  }
  if (lane == 0) {
    const float* bb = be + sc * 4;
    float4 r;
    r.x = (c < 0) ? 0.f : fmaxf(p0 + bb[0], 0.f);
    r.y = (c < 0) ? 0.f : fmaxf(p1 + bb[1], 0.f);
    r.z = (c < 0) ? 0.f : fmaxf(p2 + bb[2], 0.f);
    r.w = (c < 0) ? 0.f : fmaxf(p3 + bb[3], 0.f);
    *(float4*)&enc[n * 4] = r;
  }
}

// agg[n,d] = (1/cnt) * sum_{sel edges} relu(Wd[c,d,:]·enc[src] + bd[c,d])
__global__ __launch_bounds__(256) void agg_kernel(const float* __restrict__ enc,
                                                  const int* __restrict__ labels,
                                                  const int* __restrict__ off,
                                                  const int* __restrict__ esrc,
                                                  const float* __restrict__ Wd,
                                                  const float* __restrict__ bd,
                                                  float* __restrict__ agg, int N) {
  int half = threadIdx.x >> 7;
  int d = threadIdx.x & 127;
  int n = blockIdx.x * 2 + half;
  if (n >= N) return;
  int c = labels[n];
  int j0 = off[n], j1 = off[n + 1];
  int cnt = j1 - j0;
  float outv = 0.f;
  if (c >= 0 && cnt > 0) {
    const float4 w = *(const float4*)&Wd[((size_t)c * DIM + d) * 4];
    const float bb = bd[(size_t)c * DIM + d];
    float acc = 0.f;
    for (int j = j0; j < j1; ++j) {
      int s = esrc[j];
      float4 m = *(const float4*)&enc[s * 4];
      float v = fmaf(w.x, m.x, fmaf(w.y, m.y, fmaf(w.z, m.z, fmaf(w.w, m.w, bb))));
      acc += fmaxf(v, 0.f);
    }
    outv = acc / (float)cnt;
  }
  agg[(size_t)n * DIM + d] = outv;
}

// Build split-bf16 weight images in per-K-chunk LDS layout:
// img[(kc*2 + hl)*BJ*40 + j*40 + kq] ; k = kc*32+kq ; hi (hl=0) / lo (hl=1).
// Also zeroes BN stats when zstats.
__global__ void wt_kernel(const float* __restrict__ Wl, const float* __restrict__ Wr,
                          ushort* __restrict__ img, float* __restrict__ stats,
                          int ncol, int BJ, int zstats) {
  int idx = blockIdx.x * 256 + threadIdx.x;
  if (zstats && idx < 256) stats[idx] = 0.f;
  int total = 8 * 2 * BJ * 40;
  if (idx >= total) return;
  int kq = idx % 40;
  int t = idx / 40;
  int j = t % BJ;
  t /= BJ;
  int hl = t & 1;
  int kc = t >> 1;
  int k = kc * 32 + kq;
  float v = 0.f;
  if (kq < 32 && j < ncol) v = (k < 128) ? Wl[j * 128 + k] : Wr[j * 128 + (k - 128)];
  ushort hi = f2bf(v);
  ushort ov = hi;
  if (hl) ov = f2bf(v - bf2f(hi));
  img[idx] = ov;
}

// out[n,j] = bias[j] + sum_k [agg|h][n,k] * W[j,k]  via split-bf16 MFMA.
// BM=128 rows/block, 4 waves. NCOL=128: wave grid 2x2 (64x64 each).
// NCOL=40: 4 waves x 32 rows, 3 col-frags (48, masked to 40).
// If stats != null, accumulates col sums / sumsq (bias included) for BN.
template <int NCOL>
__global__ __launch_bounds__(256) void linear_mfma(const float* __restrict__ agg,
                                                   const float* __restrict__ h,
                                                   const ushort* __restrict__ img,
                                                   const float* __restrict__ bias,
                                                   float* __restrict__ out,
                                                   float* __restrict__ stats, int N) {
  constexpr int BJ = (NCOL == 128) ? 128 : 48;
  constexpr int MF = (NCOL == 128) ? 4 : 2;
  constexpr int NF = (NCOL == 128) ? 4 : 3;
  __shared__ __align__(16) ushort Alds[2][128][40];
  __shared__ __align__(16) ushort Blds[2][BJ][40];
  const int tid = threadIdx.x;
  const int w = tid >> 6, l = tid & 63;
  const int r0 = blockIdx.x * 128;
  const int wrow = (NCOL == 128) ? (w >> 1) * 64 : w * 32;
  const int wcol = (NCOL == 128) ? (w & 1) * 64 : 0;

  f32x4 acc[MF][NF];
#pragma unroll
  for (int m = 0; m < MF; ++m)
#pragma unroll
    for (int n = 0; n < NF; ++n) acc[m][n] = (f32x4){0.f, 0.f, 0.f, 0.f};

  const int kg = (l >> 4) * 8;  // k-element offset of this lane's fragment slice

  for (int kc = 0; kc < 8; ++kc) {
    const float* __restrict__ src = (kc < 4) ? agg : h;
    const int kb = (kc & 3) * 32;
    // stage A: 128 rows x 32 k, fp32 -> split bf16
#pragma unroll
    for (int q = 0; q < 4; ++q) {
      int idx = q * 256 + tid;
      int row = idx >> 3, kq = idx & 7;
      float4 v = make_float4(0.f, 0.f, 0.f, 0.f);
      if (r0 + row < N) v = *(const float4*)&src[(size_t)(r0 + row) * DIM + kb + kq * 4];
      ushort4 hi4, lo4;
      hi4.x = f2bf(v.x); lo4.x = f2bf(v.x - bf2f(hi4.x));
      hi4.y = f2bf(v.y); lo4.y = f2bf(v.y - bf2f(hi4.y));
      hi4.z = f2bf(v.z); lo4.z = f2bf(v.z - bf2f(hi4.z));
      hi4.w = f2bf(v.w); lo4.w = f2bf(v.w - bf2f(hi4.w));
      *(ushort4*)&Alds[0][row][kq * 4] = hi4;
      *(ushort4*)&Alds[1][row][kq * 4] = lo4;
    }
    // stage B: flat copy of the prebuilt split image chunk
    {
      const float4* bs = (const float4*)(img + (size_t)kc * 2 * BJ * 40);
      float4* bd = (float4*)&Blds[0][0][0];
      constexpr int NV = 2 * BJ * 40 * 2 / 16;
#pragma unroll
      for (int i = 0; i < (NV + 255) / 256; ++i) {
        int idx = tid + i * 256;
        if ((NV % 256 == 0) || idx < NV) bd[idx] = bs[idx];
      }
    }
    __syncthreads();
    bf16x8 ah[MF], al[MF], bh[NF], bl[NF];
#pragma unroll
    for (int m = 0; m < MF; ++m) {
      int row = wrow + m * 16 + (l & 15);
      ah[m] = *(const bf16x8*)&Alds[0][row][kg];
      al[m] = *(const bf16x8*)&Alds[1][row][kg];
    }
#pragma unroll
    for (int n = 0; n < NF; ++n) {
      int col = wcol + n * 16 + (l & 15);
      bh[n] = *(const bf16x8*)&Blds[0][col][kg];
      bl[n] = *(const bf16x8*)&Blds[1][col][kg];
    }
#pragma unroll
    for (int m = 0; m < MF; ++m)
#pragma unroll
      for (int n = 0; n < NF; ++n) {
        acc[m][n] = __builtin_amdgcn_mfma_f32_16x16x32_bf16(ah[m], bh[n], acc[m][n], 0, 0, 0);
        acc[m][n] = __builtin_amdgcn_mfma_f32_16x16x32_bf16(al[m], bh[n], acc[m][n], 0, 0, 0);
        acc[m][n] = __builtin_amdgcn_mfma_f32_16x16x32_bf16(ah[m], bl[n], acc[m][n], 0, 0, 0);
      }
    __syncthreads();
  }

  // epilogue: bias, store, (optional) BN stats
  if constexpr (NCOL == 128) {
#pragma unroll
    for (int n = 0; n < NF; ++n) {
      int col = wcol + n * 16 + (l & 15);
      float bv = bias[col];
      float s = 0.f, q2 = 0.f;
#pragma unroll
      for (int m = 0; m < MF; ++m) {
#pragma unroll
        for (int r = 0; r < 4; ++r) {
          int row = r0 + wrow + m * 16 + (l >> 4) * 4 + r;
          if (row < N) {
            float v = acc[m][n][r] + bv;
            out[(size_t)row * DIM + col] = v;
            s += v;
            q2 = fmaf(v, v, q2);
          }
        }
      }
      s += __shfl_xor(s, 16); s += __shfl_xor(s, 32);
      q2 += __shfl_xor(q2, 16); q2 += __shfl_xor(q2, 32);
      if (stats != nullptr && l < 16) {
        atomicAdd(&stats[col], s);
        atomicAdd(&stats[DIM + col], q2);
      }
    }
  } else {
#pragma unroll
    for (int n = 0; n < NF; ++n) {
      int col = n * 16 + (l & 15);
      if (col < NCOL) {
        float bv = bias[col];
#pragma unroll
        for (int m = 0; m < MF; ++m) {
#pragma unroll
          for (int r = 0; r < 4; ++r) {
            int row = r0 + wrow + m * 16 + (l >> 4) * 4 + r;
            if (row < N) out[(size_t)row * NCOL + col] = acc[m][n][r] + bv;
          }
        }
      }
    }
  }
}

// ---------------- host ----------------

extern "C" void kernel_launch(void* const* d_in, const int* in_sizes, int n_in,
                              void* d_out, int out_size, void* d_ws, size_t ws_size,
                              hipStream_t stream) {
  const float* x      = (const float*)d_in[0];
  const int*   ei     = (const int*)d_in[1];
  const int*   labels = (const int*)d_in[2];
  const float* conf   = (const float*)d_in[3];
  const float* W_enc  = (const float*)d_in[4];
  const float* b_enc  = (const float*)d_in[5];
  const float* W_dec  = (const float*)d_in[6];
  const float* b_dec  = (const float*)d_in[7];
  const float* Wl01   = (const float*)d_in[8];
  const float* bl01   = (const float*)d_in[9];
  const float* Wr01   = (const float*)d_in[10];
  const float* Wl2    = (const float*)d_in[11];
  const float* bl2    = (const float*)d_in[12];
  const float* Wr2    = (const float*)d_in[13];
  const float* gamma  = (const float*)d_in[14];
  const float* beta   = (const float*)d_in[15];
  float* out = (float*)d_out;

  const int N = in_sizes[2];
  const int E = in_sizes[3];

  char* ws = (char*)d_ws;
  size_t o = 0;
  auto alloc = [&](size_t bytes) -> void* {
    void* p = ws + o;
    o += (bytes + 255) & ~(size_t)255;
    return p;
  };
  int* cnt     = (int*)alloc((size_t)N * 4);
  int* off     = (int*)alloc(((size_t)N + 1) * 4);
  int* pos     = (int*)alloc((size_t)N * 4);
  int* esrc    = (int*)alloc((size_t)E * 4);
  float* enc   = (float*)alloc((size_t)N * 4 * 4);
  float* agg   = (float*)alloc((size_t)N * DIM * 4);
  float* hbuf  = (float*)alloc((size_t)N * DIM * 4);
  ushort* img  = (ushort*)alloc((size_t)8 * 2 * 128 * 40 * 2);
  float* stats = (float*)alloc(256 * 4);
  (void)ws_size; (void)n_in; (void)out_size;

  zero_cnt_kernel<<<(N + 255) / 256, 256, 0, stream>>>(cnt, N);
  hist_kernel<<<(E + 255) / 256, 256, 0, stream>>>(ei, conf, cnt, E);
  scan_kernel<<<1, 1024, 0, stream>>>(cnt, off, pos, N);
  fill_kernel<<<(E + 255) / 256, 256, 0, stream>>>(ei, conf, pos, esrc, E);

  const int gemm_blocks = (N + 127) / 128;
  const float* hin = x;
  for (int l = 0; l < 3; ++l) {
    const float* We = W_enc + (size_t)l * CLS * 4 * DIM;
    const float* be = b_enc + (size_t)l * CLS * 4;
    const float* Wd = W_dec + (size_t)l * CLS * DIM * 4;
    const float* bd = b_dec + (size_t)l * CLS * DIM;
    // enc (+ fused BN+relu of previous layer's linear output, in-place on hbuf)
    enc_kernel<<<(N + 3) / 4, 256, 0, stream>>>(
        hin, labels, We, be, enc, hbuf, stats,
        gamma + (l > 0 ? (l - 1) * DIM : 0), beta + (l > 0 ? (l - 1) * DIM : 0),
        (l > 0) ? 1 : 0, N);
    agg_kernel<<<(N + 1) / 2, 256, 0, stream>>>(enc, labels, off, esrc, Wd, bd, agg, N);
    if (l < 2) {
      const float* Wl = Wl01 + (size_t)l * DIM * DIM;
      const float* Wr = Wr01 + (size_t)l * DIM * DIM;
      const float* bl = bl01 + (size_t)l * DIM;
      int total = 8 * 2 * 128 * 40;
      wt_kernel<<<(total + 255) / 256, 256, 0, stream>>>(Wl, Wr, img, stats, 128, 128, 1);
      linear_mfma<128><<<gemm_blocks, 256, 0, stream>>>(agg, hin, img, bl, hbuf, stats, N);
      hin = hbuf;
    } else {
      int total = 8 * 2 * 48 * 40;
      wt_kernel<<<(total + 255) / 256, 256, 0, stream>>>(Wl2, Wr2, img, stats, 40, 48, 0);
      linear_mfma<40><<<gemm_blocks, 256, 0, stream>>>(agg, hin, img, bl2, out, nullptr, N);
    }
  }
}